// Round 7
// baseline (415.903 us; speedup 1.0000x reference)
//
#include <hip/hip_runtime.h>
#include <math.h>

#define N_NODES 50000
#define N_EDGES 800000
#define EP (N_EDGES + N_NODES) /* 850000 edges incl self-loops */
#define NEG_SLOPE 0.2f
#define SCAN_BLOCKS ((N_NODES + 255) / 256) /* 196 */

typedef short short8 __attribute__((ext_vector_type(8)));
typedef float float4_ __attribute__((ext_vector_type(4)));

__device__ __forceinline__ unsigned short f2bf(float f) {
  unsigned int u = __float_as_uint(f);
  u = (u + 0x7FFFu + ((u >> 16) & 1u)) >> 16;  // RNE
  return (unsigned short)u;
}
__device__ __forceinline__ float bf2f(unsigned int us) {
  return __uint_as_float(us << 16);
}
__device__ __forceinline__ unsigned int pack2(float lo, float hi) {
  return (unsigned int)f2bf(lo) | ((unsigned int)f2bf(hi) << 16);
}

// Column permutation: storage position p holds true column perm(p).
__device__ __forceinline__ int permc(int p) {
  return ((p & 0xE) << 4) | ((p & 1) << 4) | (p >> 4);
}

// ---------------- fused setup: W1/W2/W3 -> fragment-major bf16, bias permute ----------------
// grid = 67 blocks x 256.

__global__ void setup_kernel(const float* __restrict__ W1, const float* __restrict__ W2,
                             const float* __restrict__ W3, const float* __restrict__ b1,
                             const float* __restrict__ b2,
                             unsigned short* __restrict__ Wf1, unsigned short* __restrict__ Wf2,
                             unsigned short* __restrict__ Wf3,
                             float* __restrict__ pb1, float* __restrict__ pb2) {
  int blk = blockIdx.x;
  int tid = threadIdx.x;
  if (blk < 64) {
    int perm = blk >= 32;
    const float* W = perm ? W2 : W1;
    unsigned short* Wf = perm ? Wf2 : Wf1;
    int t = (blk & 31) * 256 + tid;
    int f = t >> 6, lane = t & 63;
    int nt = f >> 3, k0t = f & 7;
    int lm = lane & 15, kg = lane >> 4;
    int kbase = k0t * 32 + kg * 8;
    int n = nt * 16 + lm;
    short8 v;
#pragma unroll
    for (int j = 0; j < 8; ++j) {
      int k = perm ? permc(kbase + j) : (kbase + j);
      v[j] = (short)f2bf(W[(size_t)k * 256 + n]);
    }
    ((short8*)Wf)[t] = v;
  } else if (blk < 66) {
    int t = (blk - 64) * 256 + tid;  // 512 threads
    int k0t = t >> 6, lane = t & 63;
    int lm = lane & 15, kg = lane >> 4;
    int kbase = k0t * 32 + kg * 8;
    short8 v;
#pragma unroll
    for (int j = 0; j < 8; ++j) {
      int k = permc(kbase + j);
      v[j] = (lm < 10) ? (short)f2bf(W3[(size_t)k * 10 + lm]) : (short)0;
    }
    ((short8*)Wf3)[t] = v;
  } else {
    int c = permc(tid);
    pb1[tid] = b1[c];
    pb2[tid] = b2[c];
  }
}

// ---------------- CSR build ----------------

__global__ void count_kernel(const int* __restrict__ ei, int* __restrict__ cnt) {
  int e = blockIdx.x * 256 + threadIdx.x;
  if (e >= EP) return;
  int dst = (e < N_EDGES) ? ei[N_EDGES + e] : (e - N_EDGES);
  atomicAdd(&cnt[dst], 1);
}

__global__ void scan1_kernel(const int* __restrict__ cnt, int* __restrict__ off,
                             int* __restrict__ bsum) {
  int i = blockIdx.x * 256 + threadIdx.x;
  int v = (i < N_NODES) ? cnt[i] : 0;
  int lane = threadIdx.x & 63, w = threadIdx.x >> 6;
  int x = v;
  for (int o = 1; o < 64; o <<= 1) { int y = __shfl_up(x, o); if (lane >= o) x += y; }
  __shared__ int wsum[4];
  if (lane == 63) wsum[w] = x;
  __syncthreads();
  int add = 0;
  for (int k = 0; k < w; ++k) add += wsum[k];
  if (i < N_NODES) off[i] = x - v + add;  // block-local exclusive
  if (threadIdx.x == 255) bsum[blockIdx.x] = add + x;
}

__global__ void scan2_kernel(int* __restrict__ bsum, int* __restrict__ bpre,
                             int* __restrict__ off) {
  int t = threadIdx.x;
  int v = (t < SCAN_BLOCKS) ? bsum[t] : 0;
  int lane = t & 63, w = t >> 6;
  int x = v;
  for (int o = 1; o < 64; o <<= 1) { int y = __shfl_up(x, o); if (lane >= o) x += y; }
  __shared__ int wsum[4];
  if (lane == 63) wsum[w] = x;
  __syncthreads();
  int add = 0;
  for (int k = 0; k < w; ++k) add += wsum[k];
  if (t < SCAN_BLOCKS) bpre[t] = x - v + add;
  if (t == 255) off[N_NODES] = add + x;  // grand total == EP
}

__global__ void scan3_kernel(int* __restrict__ off, const int* __restrict__ bpre) {
  int i = blockIdx.x * 256 + threadIdx.x;
  if (i < N_NODES) off[i] += bpre[blockIdx.x];
}

// pos = off[dst] + (atomicSub(cnt)-1): within-segment order is irrelevant downstream.
__global__ void scatter_kernel(const int* __restrict__ ei, const int* __restrict__ off,
                               int* __restrict__ cnt, int* __restrict__ esrc) {
  int e = blockIdx.x * 256 + threadIdx.x;
  if (e >= EP) return;
  int src, dst;
  if (e < N_EDGES) { src = ei[e]; dst = ei[N_EDGES + e]; }
  else { src = dst = e - N_EDGES; }
  int pos = off[dst] + atomicSub(&cnt[dst], 1) - 1;
  esrc[pos] = src;
}

// ---- bf16 MFMA GEMM, B in LDS, permuted-C epilogue + fused alpha ----
// 384 threads = 6 waves, 32 rows/wave -> 192 rows/block; grid = 261 (~1.02 blocks/CU).

template <int AF32>
__global__ __launch_bounds__(384, 1) void gemm_mfma4(const void* __restrict__ Av,
                                                     const uint4* __restrict__ Wf,
                                                     unsigned short* __restrict__ C,
                                                     const float* __restrict__ asrc,
                                                     const float* __restrict__ adst,
                                                     float* __restrict__ as_,
                                                     float* __restrict__ ad_, int M) {
  __shared__ uint4 Bl[8192];  // 128 KB
  int tid = threadIdx.x;
  for (int i = tid; i < 8192; i += 384) Bl[i] = Wf[i];
  int wave = tid >> 6, lane = tid & 63;
  int lm = lane & 15, kg = lane >> 4;
  int row0 = blockIdx.x * 192 + wave * 32;
  int ar0 = row0 + lm, ar1 = row0 + 16 + lm;
  if (ar0 >= M) ar0 = M - 1;
  if (ar1 >= M) ar1 = M - 1;
  float4_ acc0[16], acc1[16];
#pragma unroll
  for (int i = 0; i < 16; ++i) { acc0[i] = (float4_){0, 0, 0, 0}; acc1[i] = (float4_){0, 0, 0, 0}; }
  __syncthreads();
  const short8* Bf = (const short8*)Bl;
  for (int k0t = 0; k0t < 8; ++k0t) {
    int k0 = k0t * 32;
    short8 a0, a1;
    if (AF32) {
      const float* A = (const float*)Av;
      const float* p0 = A + (size_t)ar0 * 256 + kg * 8 + k0;
      const float* p1 = A + (size_t)ar1 * 256 + kg * 8 + k0;
      float4 f0 = *(const float4*)p0, f1 = *(const float4*)(p0 + 4);
      float4 g0 = *(const float4*)p1, g1 = *(const float4*)(p1 + 4);
      a0 = (short8){(short)f2bf(f0.x), (short)f2bf(f0.y), (short)f2bf(f0.z), (short)f2bf(f0.w),
                    (short)f2bf(f1.x), (short)f2bf(f1.y), (short)f2bf(f1.z), (short)f2bf(f1.w)};
      a1 = (short8){(short)f2bf(g0.x), (short)f2bf(g0.y), (short)f2bf(g0.z), (short)f2bf(g0.w),
                    (short)f2bf(g1.x), (short)f2bf(g1.y), (short)f2bf(g1.z), (short)f2bf(g1.w)};
    } else {
      const unsigned short* A = (const unsigned short*)Av;
      a0 = *(const short8*)(A + (size_t)ar0 * 256 + kg * 8 + k0);
      a1 = *(const short8*)(A + (size_t)ar1 * 256 + kg * 8 + k0);
    }
#pragma unroll
    for (int nt = 0; nt < 16; ++nt) {
      short8 b = Bf[(nt * 8 + k0t) * 64 + lane];
      acc0[nt] = __builtin_amdgcn_mfma_f32_16x16x32_bf16(a0, b, acc0[nt], 0, 0, 0);
      acc1[nt] = __builtin_amdgcn_mfma_f32_16x16x32_bf16(a1, b, acc1[nt], 0, 0, 0);
    }
  }
  // epilogue: permuted-C coalesced stores + fused alpha (from fp32 acc, true cols)
  float avs[16], avd[16];
#pragma unroll
  for (int nt = 0; nt < 16; ++nt) { avs[nt] = asrc[nt * 16 + lm]; avd[nt] = adst[nt * 16 + lm]; }
#pragma unroll
  for (int g = 0; g < 2; ++g) {
    int rbase = row0 + g * 16 + kg * 4;
#pragma unroll
    for (int i = 0; i < 4; ++i) {
      int r = rbase + i;
      float s = 0.f, dd = 0.f;
      unsigned int u[8];
#pragma unroll
      for (int j = 0; j < 8; ++j) {
        float vlo = g ? acc1[2 * j][i] : acc0[2 * j][i];
        float vhi = g ? acc1[2 * j + 1][i] : acc0[2 * j + 1][i];
        u[j] = pack2(vlo, vhi);
        s += vlo * avs[2 * j] + vhi * avs[2 * j + 1];
        dd += vlo * avd[2 * j] + vhi * avd[2 * j + 1];
      }
      if (r < M) {
        uint4* cp = (uint4*)(C + (size_t)r * 256 + lm * 16);
        cp[0] = (uint4){u[0], u[1], u[2], u[3]};
        cp[1] = (uint4){u[4], u[5], u[6], u[7]};
      }
#pragma unroll
      for (int o = 1; o < 16; o <<= 1) { s += __shfl_xor(s, o); dd += __shfl_xor(dd, o); }
      if (lm == 0 && r < M) { as_[r] = s; ad_[r] = dd; }
    }
  }
}

// ---- layer-3 MFMA GEMM: permuted-k A @ permuted-k Wf3, padded h3 [N,16] + fused alpha ----

__global__ __launch_bounds__(256) void gemm_c3_kernel(const unsigned short* __restrict__ X,
                                                      const unsigned short* __restrict__ Wf3,
                                                      const float* __restrict__ asrc,
                                                      const float* __restrict__ adst,
                                                      float* __restrict__ h3p,
                                                      float* __restrict__ as_,
                                                      float* __restrict__ ad_, int M) {
  int tid = threadIdx.x;
  int wave = tid >> 6, lane = tid & 63;
  int lm = lane & 15, kg = lane >> 4;
  int row0 = blockIdx.x * 128 + wave * 32;
  int ar0 = row0 + lm, ar1 = row0 + 16 + lm;
  if (ar0 >= M) ar0 = M - 1;
  if (ar1 >= M) ar1 = M - 1;
  short8 bf[8];
#pragma unroll
  for (int k0t = 0; k0t < 8; ++k0t) bf[k0t] = ((const short8*)Wf3)[k0t * 64 + lane];
  float4_ acc0 = (float4_){0, 0, 0, 0}, acc1 = (float4_){0, 0, 0, 0};
#pragma unroll
  for (int k0t = 0; k0t < 8; ++k0t) {
    int k0 = k0t * 32;
    short8 a0 = *(const short8*)(X + (size_t)ar0 * 256 + kg * 8 + k0);
    short8 a1 = *(const short8*)(X + (size_t)ar1 * 256 + kg * 8 + k0);
    acc0 = __builtin_amdgcn_mfma_f32_16x16x32_bf16(a0, bf[k0t], acc0, 0, 0, 0);
    acc1 = __builtin_amdgcn_mfma_f32_16x16x32_bf16(a1, bf[k0t], acc1, 0, 0, 0);
  }
  float avs = (lm < 10) ? asrc[lm] : 0.f;
  float avd = (lm < 10) ? adst[lm] : 0.f;
#pragma unroll
  for (int g = 0; g < 2; ++g) {
    int rbase = row0 + g * 16 + kg * 4;
#pragma unroll
    for (int i = 0; i < 4; ++i) {
      int r = rbase + i;
      float v = g ? acc1[i] : acc0[i];
      if (r < M) h3p[(size_t)r * 16 + lm] = v;  // padded row (cols 10..15 are zero)
      float s = v * avs, dd = v * avd;
#pragma unroll
      for (int o = 1; o < 16; o <<= 1) { s += __shfl_xor(s, o); dd += __shfl_xor(dd, o); }
      if (lm == 0 && r < M) { as_[r] = s; ad_[r] = dd; }
    }
  }
}

// ---- fused softmax + aggregation (layers 1&2): one wave per dst, 2 edges/load, unroll 4 ----

__global__ __launch_bounds__(256) void agg_fused_kernel(const int* __restrict__ off,
                                                        const int* __restrict__ esrc,
                                                        const float* __restrict__ as_,
                                                        const float* __restrict__ ad_,
                                                        const unsigned short* __restrict__ h,
                                                        const float* __restrict__ pbias,
                                                        unsigned short* __restrict__ outg) {
  __shared__ int s_src[4][64];
  __shared__ float s_p[4][64];
  int wave = threadIdx.x >> 6, lane = threadIdx.x & 63;
  int pair = lane >> 5, cl = lane & 31;  // lane covers storage cols [8*cl, 8*cl+8)
  int d = blockIdx.x * 4 + wave;
  int s0 = off[d], s1 = off[d + 1];
  float adv = ad_[d];
  const uint4* hp4 = (const uint4*)h;
  float a0 = 0.f, a1 = 0.f, a2 = 0.f, a3 = 0.f, a4 = 0.f, a5 = 0.f, a6 = 0.f, a7 = 0.f;
  float sum = 0.f;
  for (int base = s0; base < s1; base += 64) {
    int m = s1 - base; if (m > 64) m = 64;
    int sv = 0; float p = 0.f;
    if (lane < m) {
      sv = esrc[base + lane];
      float e = as_[sv] + adv;
      e = e > 0.f ? e : NEG_SLOPE * e;
      p = __expf(e);
    }
    s_src[wave][lane] = sv;
    s_p[wave][lane] = p;
    float ps = p;
    for (int o = 32; o; o >>= 1) ps += __shfl_xor(ps, o);
    sum += ps;
    int nb = (m + 1) >> 1;  // batches of 2 edges (one per half-wave)
    int j = 0;
    for (; j + 4 <= nb; j += 4) {
#pragma unroll
      for (int u = 0; u < 4; ++u) {
        int idx = (j + u) * 2 + pair;
        int src = s_src[wave][idx];
        float w = s_p[wave][idx];
        uint4 pv = hp4[(size_t)src * 32 + cl];
        a0 = fmaf(w, bf2f(pv.x & 0xffffu), a0); a1 = fmaf(w, bf2f(pv.x >> 16), a1);
        a2 = fmaf(w, bf2f(pv.y & 0xffffu), a2); a3 = fmaf(w, bf2f(pv.y >> 16), a3);
        a4 = fmaf(w, bf2f(pv.z & 0xffffu), a4); a5 = fmaf(w, bf2f(pv.z >> 16), a5);
        a6 = fmaf(w, bf2f(pv.w & 0xffffu), a6); a7 = fmaf(w, bf2f(pv.w >> 16), a7);
      }
    }
    for (; j < nb; ++j) {
      int idx = j * 2 + pair;
      int src = s_src[wave][idx];
      float w = s_p[wave][idx];
      uint4 pv = hp4[(size_t)src * 32 + cl];
      a0 = fmaf(w, bf2f(pv.x & 0xffffu), a0); a1 = fmaf(w, bf2f(pv.x >> 16), a1);
      a2 = fmaf(w, bf2f(pv.y & 0xffffu), a2); a3 = fmaf(w, bf2f(pv.y >> 16), a3);
      a4 = fmaf(w, bf2f(pv.z & 0xffffu), a4); a5 = fmaf(w, bf2f(pv.z >> 16), a5);
      a6 = fmaf(w, bf2f(pv.w & 0xffffu), a6); a7 = fmaf(w, bf2f(pv.w >> 16), a7);
    }
  }
  a0 += __shfl_xor(a0, 32); a1 += __shfl_xor(a1, 32);
  a2 += __shfl_xor(a2, 32); a3 += __shfl_xor(a3, 32);
  a4 += __shfl_xor(a4, 32); a5 += __shfl_xor(a5, 32);
  a6 += __shfl_xor(a6, 32); a7 += __shfl_xor(a7, 32);
  if (pair == 0) {
    float inv = 1.0f / sum;
    float4 b0 = ((const float4*)pbias)[2 * cl];
    float4 b1 = ((const float4*)pbias)[2 * cl + 1];
    float o0 = fmaxf(fmaf(a0, inv, b0.x), 0.f);
    float o1 = fmaxf(fmaf(a1, inv, b0.y), 0.f);
    float o2 = fmaxf(fmaf(a2, inv, b0.z), 0.f);
    float o3 = fmaxf(fmaf(a3, inv, b0.w), 0.f);
    float o4 = fmaxf(fmaf(a4, inv, b1.x), 0.f);
    float o5 = fmaxf(fmaf(a5, inv, b1.y), 0.f);
    float o6 = fmaxf(fmaf(a6, inv, b1.z), 0.f);
    float o7 = fmaxf(fmaf(a7, inv, b1.w), 0.f);
    uint4 ov = (uint4){pack2(o0, o1), pack2(o2, o3), pack2(o4, o5), pack2(o6, o7)};
    ((uint4*)outg)[(size_t)d * 32 + cl] = ov;
  }
}

// ---- layer-3 fused softmax+agg, D=10: one wave per dst, lane-parallel edges ----
// h3p padded [N,16] f32; 4 lanes x float4 cover one edge row -> 16 edges/instr.

__global__ __launch_bounds__(256) void agg10_fused_kernel(const int* __restrict__ off,
                                                          const int* __restrict__ esrc,
                                                          const float* __restrict__ as_,
                                                          const float* __restrict__ ad_,
                                                          const float* __restrict__ h3p,
                                                          const float* __restrict__ bias,
                                                          float* __restrict__ out) {
  __shared__ int s_src[4][64];
  __shared__ float s_p[4][64];
  int wave = threadIdx.x >> 6, lane = threadIdx.x & 63;
  int d = blockIdx.x * 4 + wave;
  if (d >= N_NODES) return;
  int s0 = off[d], s1 = off[d + 1];
  float adv = ad_[d];
  int er = lane >> 2;   // edge slot within group of 16
  int part = lane & 3;  // float4 quarter of the padded row
  float ax = 0.f, ay = 0.f, az = 0.f, aw = 0.f;
  float sum = 0.f;
  const float4* hp = (const float4*)h3p;
  for (int base = s0; base < s1; base += 64) {
    int m = s1 - base; if (m > 64) m = 64;
    int sv = 0; float p = 0.f;
    if (lane < m) {
      sv = esrc[base + lane];
      float e = as_[sv] + adv;
      e = e > 0.f ? e : NEG_SLOPE * e;
      p = __expf(e);
    }
    s_src[wave][lane] = sv;
    s_p[wave][lane] = p;
    float ps = p;
    for (int o = 32; o; o >>= 1) ps += __shfl_xor(ps, o);
    sum += ps;
    int ng = (m + 15) >> 4;
    for (int g = 0; g < ng; ++g) {
      int idx = g * 16 + er;
      int src = s_src[wave][idx];
      float w = s_p[wave][idx];  // 0 for padded slots
      float4 v = hp[(size_t)src * 4 + part];
      ax = fmaf(w, v.x, ax); ay = fmaf(w, v.y, ay);
      az = fmaf(w, v.z, az); aw = fmaf(w, v.w, aw);
    }
  }
  // reduce over the 16 edge-slots (lanes sharing `part`)
  for (int o = 4; o < 64; o <<= 1) {
    ax += __shfl_xor(ax, o); ay += __shfl_xor(ay, o);
    az += __shfl_xor(az, o); aw += __shfl_xor(aw, o);
  }
  if (lane < 3) {  // lane == part here (er==0): cols [4*lane, 4*lane+4), need 0..9
    float inv = 1.0f / sum;
    float* op = out + (size_t)d * 10 + 4 * lane;
    float2 lo = {fmaf(ax, inv, bias[4 * lane]), fmaf(ay, inv, bias[4 * lane + 1])};
    *(float2*)op = lo;
    if (lane < 2) {
      float2 hi = {fmaf(az, inv, bias[4 * lane + 2]), fmaf(aw, inv, bias[4 * lane + 3])};
      *(float2*)(op + 2) = hi;
    }
  }
}

// ---------------- launch ----------------

extern "C" void kernel_launch(void* const* d_in, const int* in_sizes, int n_in,
                              void* d_out, int out_size, void* d_ws, size_t ws_size,
                              hipStream_t stream) {
  const float* x   = (const float*)d_in[0];
  const int*   ei  = (const int*)d_in[1];
  const float* W1  = (const float*)d_in[2];
  const float* as1 = (const float*)d_in[3];
  const float* ad1 = (const float*)d_in[4];
  const float* b1  = (const float*)d_in[5];
  const float* W2  = (const float*)d_in[6];
  const float* as2 = (const float*)d_in[7];
  const float* ad2 = (const float*)d_in[8];
  const float* b2  = (const float*)d_in[9];
  const float* W3  = (const float*)d_in[10];
  const float* as3 = (const float*)d_in[11];
  const float* ad3 = (const float*)d_in[12];
  const float* b3  = (const float*)d_in[13];
  float* out = (float*)d_out;

  char* ws = (char*)d_ws;
  size_t off_b = 0;
  auto alloc = [&](size_t bytes) -> char* {
    char* p = ws + off_b;
    off_b += (bytes + 255) & ~(size_t)255;
    return p;
  };
  unsigned short* hb   = (unsigned short*)alloc((size_t)N_NODES * 256 * 2);
  unsigned short* gb   = (unsigned short*)alloc((size_t)N_NODES * 256 * 2);
  unsigned short* Wf1  = (unsigned short*)alloc(256 * 256 * 2);
  unsigned short* Wf2  = (unsigned short*)alloc(256 * 256 * 2);
  unsigned short* Wf3  = (unsigned short*)alloc(8 * 64 * 8 * 2);
  float* pb1   = (float*)alloc(256 * 4);
  float* pb2   = (float*)alloc(256 * 4);
  float* h3p   = (float*)alloc((size_t)N_NODES * 16 * 4);
  float* as_   = (float*)alloc((size_t)N_NODES * 4);
  float* ad_   = (float*)alloc((size_t)N_NODES * 4);
  int*   roff  = (int*)alloc((size_t)(N_NODES + 1) * 4);
  int*   cnt   = (int*)alloc((size_t)N_NODES * 4);
  int*   bsum  = (int*)alloc((size_t)SCAN_BLOCKS * 4);
  int*   bpre  = (int*)alloc((size_t)SCAN_BLOCKS * 4);
  int*   esrc  = (int*)alloc((size_t)EP * 4);

  setup_kernel<<<67, 256, 0, stream>>>(W1, W2, W3, b1, b2, Wf1, Wf2, Wf3, pb1, pb2);

  // CSR build (once; graph identical across the 3 layers)
  hipMemsetAsync(cnt, 0, N_NODES * 4, stream);
  int eb = (EP + 255) / 256;
  count_kernel<<<eb, 256, 0, stream>>>(ei, cnt);
  scan1_kernel<<<SCAN_BLOCKS, 256, 0, stream>>>(cnt, roff, bsum);
  scan2_kernel<<<1, 256, 0, stream>>>(bsum, bpre, roff);
  scan3_kernel<<<SCAN_BLOCKS, 256, 0, stream>>>(roff, bpre);
  scatter_kernel<<<eb, 256, 0, stream>>>(ei, roff, cnt, esrc);  // consumes cnt via atomicSub

  int g4blocks = (N_NODES + 191) / 192;  // 261 (~1.02 blocks/CU)
  int g3blocks = (N_NODES + 127) / 128;  // 391
  int ablocks = (N_NODES + 3) / 4;       // 12500

  // layer 1 (A = x in f32; C permuted)
  gemm_mfma4<1><<<g4blocks, 384, 0, stream>>>(x, (const uint4*)Wf1, hb, as1, ad1, as_, ad_, N_NODES);
  agg_fused_kernel<<<ablocks, 256, 0, stream>>>(roff, esrc, as_, ad_, hb, pb1, gb);
  // layer 2 (A = gb permuted; Wf2 k-permuted to match)
  gemm_mfma4<0><<<g4blocks, 384, 0, stream>>>(gb, (const uint4*)Wf2, hb, as2, ad2, as_, ad_, N_NODES);
  agg_fused_kernel<<<ablocks, 256, 0, stream>>>(roff, esrc, as_, ad_, hb, pb2, gb);
  // layer 3 (Wf3 k-permuted; padded h3)
  gemm_c3_kernel<<<g3blocks, 256, 0, stream>>>(gb, Wf3, as3, ad3, h3p, as_, ad_, N_NODES);
  agg10_fused_kernel<<<ablocks, 256, 0, stream>>>(roff, esrc, as_, ad_, h3p, b3, out);
}

// Round 8
// 373.991 us; speedup vs baseline: 1.1121x; 1.1121x over previous
//
#include <hip/hip_runtime.h>
#include <math.h>

#define N_NODES 50000
#define N_EDGES 800000
#define EP (N_EDGES + N_NODES) /* 850000 edges incl self-loops */
#define NEG_SLOPE 0.2f
#define SCAN_BLOCKS ((N_NODES + 255) / 256) /* 196 */
#define COUNT_BLOCKS ((EP + 255) / 256)     /* 3321 */

typedef short short8 __attribute__((ext_vector_type(8)));
typedef float float4_ __attribute__((ext_vector_type(4)));

__device__ __forceinline__ unsigned short f2bf(float f) {
  unsigned int u = __float_as_uint(f);
  u = (u + 0x7FFFu + ((u >> 16) & 1u)) >> 16;  // RNE
  return (unsigned short)u;
}
__device__ __forceinline__ float bf2f(unsigned int us) {
  return __uint_as_float(us << 16);
}
__device__ __forceinline__ unsigned int pack2(float lo, float hi) {
  return (unsigned int)f2bf(lo) | ((unsigned int)f2bf(hi) << 16);
}

// Column permutation: storage position p holds true column perm(p).
__device__ __forceinline__ int permc(int p) {
  return ((p & 0xE) << 4) | ((p & 1) << 4) | (p >> 4);
}

// ---- fused setup: W1/W2/W3 -> fragment-major bf16, bias permute, degree count ----
// blocks 0..63: W1/W2; 64..65: W3; 66: bias; 67..: count (cnt pre-zeroed by memset).

__global__ void setup_kernel(const float* __restrict__ W1, const float* __restrict__ W2,
                             const float* __restrict__ W3, const float* __restrict__ b1,
                             const float* __restrict__ b2, const int* __restrict__ ei,
                             unsigned short* __restrict__ Wf1, unsigned short* __restrict__ Wf2,
                             unsigned short* __restrict__ Wf3,
                             float* __restrict__ pb1, float* __restrict__ pb2,
                             int* __restrict__ cnt) {
  int blk = blockIdx.x;
  int tid = threadIdx.x;
  if (blk >= 67) {
    int e = (blk - 67) * 256 + tid;
    if (e < EP) {
      int dst = (e < N_EDGES) ? ei[N_EDGES + e] : (e - N_EDGES);
      atomicAdd(&cnt[dst], 1);
    }
    return;
  }
  if (blk < 64) {
    int perm = blk >= 32;
    const float* W = perm ? W2 : W1;
    unsigned short* Wf = perm ? Wf2 : Wf1;
    int t = (blk & 31) * 256 + tid;
    int f = t >> 6, lane = t & 63;
    int nt = f >> 3, k0t = f & 7;
    int lm = lane & 15, kg = lane >> 4;
    int kbase = k0t * 32 + kg * 8;
    int n = nt * 16 + lm;
    short8 v;
#pragma unroll
    for (int j = 0; j < 8; ++j) {
      int k = perm ? permc(kbase + j) : (kbase + j);
      v[j] = (short)f2bf(W[(size_t)k * 256 + n]);
    }
    ((short8*)Wf)[t] = v;
  } else if (blk < 66) {
    int t = (blk - 64) * 256 + tid;  // 512 threads
    int k0t = t >> 6, lane = t & 63;
    int lm = lane & 15, kg = lane >> 4;
    int kbase = k0t * 32 + kg * 8;
    short8 v;
#pragma unroll
    for (int j = 0; j < 8; ++j) {
      int k = permc(kbase + j);
      v[j] = (lm < 10) ? (short)f2bf(W3[(size_t)k * 10 + lm]) : (short)0;
    }
    ((short8*)Wf3)[t] = v;
  } else {
    int c = permc(tid);
    pb1[tid] = b1[c];
    pb2[tid] = b2[c];
  }
}

// ---------------- CSR scan + scatter ----------------

__global__ void scan1_kernel(const int* __restrict__ cnt, int* __restrict__ off,
                             int* __restrict__ bsum) {
  int i = blockIdx.x * 256 + threadIdx.x;
  int v = (i < N_NODES) ? cnt[i] : 0;
  int lane = threadIdx.x & 63, w = threadIdx.x >> 6;
  int x = v;
  for (int o = 1; o < 64; o <<= 1) { int y = __shfl_up(x, o); if (lane >= o) x += y; }
  __shared__ int wsum[4];
  if (lane == 63) wsum[w] = x;
  __syncthreads();
  int add = 0;
  for (int k = 0; k < w; ++k) add += wsum[k];
  if (i < N_NODES) off[i] = x - v + add;  // block-local exclusive
  if (threadIdx.x == 255) bsum[blockIdx.x] = add + x;
}

__global__ void scan2_kernel(int* __restrict__ bsum, int* __restrict__ bpre,
                             int* __restrict__ off) {
  int t = threadIdx.x;
  int v = (t < SCAN_BLOCKS) ? bsum[t] : 0;
  int lane = t & 63, w = t >> 6;
  int x = v;
  for (int o = 1; o < 64; o <<= 1) { int y = __shfl_up(x, o); if (lane >= o) x += y; }
  __shared__ int wsum[4];
  if (lane == 63) wsum[w] = x;
  __syncthreads();
  int add = 0;
  for (int k = 0; k < w; ++k) add += wsum[k];
  if (t < SCAN_BLOCKS) bpre[t] = x - v + add;
  if (t == 255) off[N_NODES] = add + x;  // grand total == EP
}

__global__ void scan3_kernel(int* __restrict__ off, const int* __restrict__ bpre) {
  int i = blockIdx.x * 256 + threadIdx.x;
  if (i < N_NODES) off[i] += bpre[blockIdx.x];
}

// pos = off[dst] + (atomicSub(cnt)-1): within-segment order irrelevant downstream.
__global__ void scatter_kernel(const int* __restrict__ ei, const int* __restrict__ off,
                               int* __restrict__ cnt, int* __restrict__ esrc) {
  int e = blockIdx.x * 256 + threadIdx.x;
  if (e >= EP) return;
  int src, dst;
  if (e < N_EDGES) { src = ei[e]; dst = ei[N_EDGES + e]; }
  else { src = dst = e - N_EDGES; }
  int pos = off[dst] + atomicSub(&cnt[dst], 1) - 1;
  esrc[pos] = src;
}

// ---- bf16 MFMA GEMM, B in LDS, permuted-C epilogue + fused alpha ----
// 448 threads = 7 waves x 32 rows = 224 rows/block; grid = 224 = exactly 1 round on 256 CUs.

template <int AF32>
__global__ __launch_bounds__(448, 1) void gemm_mfma4(const void* __restrict__ Av,
                                                     const uint4* __restrict__ Wf,
                                                     unsigned short* __restrict__ C,
                                                     const float* __restrict__ asrc,
                                                     const float* __restrict__ adst,
                                                     float* __restrict__ as_,
                                                     float* __restrict__ ad_, int M) {
  __shared__ uint4 Bl[8192];  // 128 KB
  int tid = threadIdx.x;
  for (int i = tid; i < 8192; i += 448) Bl[i] = Wf[i];
  int wave = tid >> 6, lane = tid & 63;
  int lm = lane & 15, kg = lane >> 4;
  int row0 = blockIdx.x * 224 + wave * 32;
  int ar0 = row0 + lm, ar1 = row0 + 16 + lm;
  if (ar0 >= M) ar0 = M - 1;
  if (ar1 >= M) ar1 = M - 1;
  float4_ acc0[16], acc1[16];
#pragma unroll
  for (int i = 0; i < 16; ++i) { acc0[i] = (float4_){0, 0, 0, 0}; acc1[i] = (float4_){0, 0, 0, 0}; }
  __syncthreads();
  const short8* Bf = (const short8*)Bl;
  for (int k0t = 0; k0t < 8; ++k0t) {
    int k0 = k0t * 32;
    short8 a0, a1;
    if (AF32) {
      const float* A = (const float*)Av;
      const float* p0 = A + (size_t)ar0 * 256 + kg * 8 + k0;
      const float* p1 = A + (size_t)ar1 * 256 + kg * 8 + k0;
      float4 f0 = *(const float4*)p0, f1 = *(const float4*)(p0 + 4);
      float4 g0 = *(const float4*)p1, g1 = *(const float4*)(p1 + 4);
      a0 = (short8){(short)f2bf(f0.x), (short)f2bf(f0.y), (short)f2bf(f0.z), (short)f2bf(f0.w),
                    (short)f2bf(f1.x), (short)f2bf(f1.y), (short)f2bf(f1.z), (short)f2bf(f1.w)};
      a1 = (short8){(short)f2bf(g0.x), (short)f2bf(g0.y), (short)f2bf(g0.z), (short)f2bf(g0.w),
                    (short)f2bf(g1.x), (short)f2bf(g1.y), (short)f2bf(g1.z), (short)f2bf(g1.w)};
    } else {
      const unsigned short* A = (const unsigned short*)Av;
      a0 = *(const short8*)(A + (size_t)ar0 * 256 + kg * 8 + k0);
      a1 = *(const short8*)(A + (size_t)ar1 * 256 + kg * 8 + k0);
    }
#pragma unroll
    for (int nt = 0; nt < 16; ++nt) {
      short8 b = Bf[(nt * 8 + k0t) * 64 + lane];
      acc0[nt] = __builtin_amdgcn_mfma_f32_16x16x32_bf16(a0, b, acc0[nt], 0, 0, 0);
      acc1[nt] = __builtin_amdgcn_mfma_f32_16x16x32_bf16(a1, b, acc1[nt], 0, 0, 0);
    }
  }
  // epilogue: permuted-C coalesced stores + fused alpha (from fp32 acc, true cols)
  float avs[16], avd[16];
#pragma unroll
  for (int nt = 0; nt < 16; ++nt) { avs[nt] = asrc[nt * 16 + lm]; avd[nt] = adst[nt * 16 + lm]; }
#pragma unroll
  for (int g = 0; g < 2; ++g) {
    int rbase = row0 + g * 16 + kg * 4;
#pragma unroll
    for (int i = 0; i < 4; ++i) {
      int r = rbase + i;
      float s = 0.f, dd = 0.f;
      unsigned int u[8];
#pragma unroll
      for (int j = 0; j < 8; ++j) {
        float vlo = g ? acc1[2 * j][i] : acc0[2 * j][i];
        float vhi = g ? acc1[2 * j + 1][i] : acc0[2 * j + 1][i];
        u[j] = pack2(vlo, vhi);
        s += vlo * avs[2 * j] + vhi * avs[2 * j + 1];
        dd += vlo * avd[2 * j] + vhi * avd[2 * j + 1];
      }
      if (r < M) {
        uint4* cp = (uint4*)(C + (size_t)r * 256 + lm * 16);
        cp[0] = (uint4){u[0], u[1], u[2], u[3]};
        cp[1] = (uint4){u[4], u[5], u[6], u[7]};
      }
#pragma unroll
      for (int o = 1; o < 16; o <<= 1) { s += __shfl_xor(s, o); dd += __shfl_xor(dd, o); }
      if (lm == 0 && r < M) { as_[r] = s; ad_[r] = dd; }
    }
  }
}

// ---- layer-3 MFMA GEMM: permuted-k A @ permuted-k Wf3 + fused alpha ----

__global__ __launch_bounds__(256) void gemm_c3_kernel(const unsigned short* __restrict__ X,
                                                      const unsigned short* __restrict__ Wf3,
                                                      const float* __restrict__ asrc,
                                                      const float* __restrict__ adst,
                                                      float* __restrict__ h3,
                                                      float* __restrict__ as_,
                                                      float* __restrict__ ad_, int M) {
  int tid = threadIdx.x;
  int wave = tid >> 6, lane = tid & 63;
  int lm = lane & 15, kg = lane >> 4;
  int row0 = blockIdx.x * 128 + wave * 32;
  int ar0 = row0 + lm, ar1 = row0 + 16 + lm;
  if (ar0 >= M) ar0 = M - 1;
  if (ar1 >= M) ar1 = M - 1;
  short8 bf[8];
#pragma unroll
  for (int k0t = 0; k0t < 8; ++k0t) bf[k0t] = ((const short8*)Wf3)[k0t * 64 + lane];
  float4_ acc0 = (float4_){0, 0, 0, 0}, acc1 = (float4_){0, 0, 0, 0};
#pragma unroll
  for (int k0t = 0; k0t < 8; ++k0t) {
    int k0 = k0t * 32;
    short8 a0 = *(const short8*)(X + (size_t)ar0 * 256 + kg * 8 + k0);
    short8 a1 = *(const short8*)(X + (size_t)ar1 * 256 + kg * 8 + k0);
    acc0 = __builtin_amdgcn_mfma_f32_16x16x32_bf16(a0, bf[k0t], acc0, 0, 0, 0);
    acc1 = __builtin_amdgcn_mfma_f32_16x16x32_bf16(a1, bf[k0t], acc1, 0, 0, 0);
  }
  float avs = (lm < 10) ? asrc[lm] : 0.f;
  float avd = (lm < 10) ? adst[lm] : 0.f;
#pragma unroll
  for (int g = 0; g < 2; ++g) {
    int rbase = row0 + g * 16 + kg * 4;
#pragma unroll
    for (int i = 0; i < 4; ++i) {
      int r = rbase + i;
      float v = g ? acc1[i] : acc0[i];
      if (r < M && lm < 10) h3[(size_t)r * 10 + lm] = v;
      float s = v * avs, dd = v * avd;
#pragma unroll
      for (int o = 1; o < 16; o <<= 1) { s += __shfl_xor(s, o); dd += __shfl_xor(dd, o); }
      if (lm == 0 && r < M) { as_[r] = s; ad_[r] = dd; }
    }
  }
}

// ---- fused softmax + aggregation (layers 1&2): one wave per dst, 2 edges/load, unroll 4 ----

__global__ __launch_bounds__(256) void agg_fused_kernel(const int* __restrict__ off,
                                                        const int* __restrict__ esrc,
                                                        const float* __restrict__ as_,
                                                        const float* __restrict__ ad_,
                                                        const unsigned short* __restrict__ h,
                                                        const float* __restrict__ pbias,
                                                        unsigned short* __restrict__ outg) {
  __shared__ int s_src[4][64];
  __shared__ float s_p[4][64];
  int wave = threadIdx.x >> 6, lane = threadIdx.x & 63;
  int pair = lane >> 5, cl = lane & 31;  // lane covers storage cols [8*cl, 8*cl+8)
  int d = blockIdx.x * 4 + wave;
  int s0 = off[d], s1 = off[d + 1];
  float adv = ad_[d];
  const uint4* hp4 = (const uint4*)h;
  float a0 = 0.f, a1 = 0.f, a2 = 0.f, a3 = 0.f, a4 = 0.f, a5 = 0.f, a6 = 0.f, a7 = 0.f;
  float sum = 0.f;
  for (int base = s0; base < s1; base += 64) {
    int m = s1 - base; if (m > 64) m = 64;
    int sv = 0; float p = 0.f;
    if (lane < m) {
      sv = esrc[base + lane];
      float e = as_[sv] + adv;
      e = e > 0.f ? e : NEG_SLOPE * e;
      p = __expf(e);
    }
    s_src[wave][lane] = sv;
    s_p[wave][lane] = p;
    float ps = p;
    for (int o = 32; o; o >>= 1) ps += __shfl_xor(ps, o);
    sum += ps;
    int nb = (m + 1) >> 1;  // batches of 2 edges (one per half-wave)
    int j = 0;
    for (; j + 4 <= nb; j += 4) {
#pragma unroll
      for (int u = 0; u < 4; ++u) {
        int idx = (j + u) * 2 + pair;
        int src = s_src[wave][idx];
        float w = s_p[wave][idx];
        uint4 pv = hp4[(size_t)src * 32 + cl];
        a0 = fmaf(w, bf2f(pv.x & 0xffffu), a0); a1 = fmaf(w, bf2f(pv.x >> 16), a1);
        a2 = fmaf(w, bf2f(pv.y & 0xffffu), a2); a3 = fmaf(w, bf2f(pv.y >> 16), a3);
        a4 = fmaf(w, bf2f(pv.z & 0xffffu), a4); a5 = fmaf(w, bf2f(pv.z >> 16), a5);
        a6 = fmaf(w, bf2f(pv.w & 0xffffu), a6); a7 = fmaf(w, bf2f(pv.w >> 16), a7);
      }
    }
    for (; j < nb; ++j) {
      int idx = j * 2 + pair;
      int src = s_src[wave][idx];
      float w = s_p[wave][idx];
      uint4 pv = hp4[(size_t)src * 32 + cl];
      a0 = fmaf(w, bf2f(pv.x & 0xffffu), a0); a1 = fmaf(w, bf2f(pv.x >> 16), a1);
      a2 = fmaf(w, bf2f(pv.y & 0xffffu), a2); a3 = fmaf(w, bf2f(pv.y >> 16), a3);
      a4 = fmaf(w, bf2f(pv.z & 0xffffu), a4); a5 = fmaf(w, bf2f(pv.z >> 16), a5);
      a6 = fmaf(w, bf2f(pv.w & 0xffffu), a6); a7 = fmaf(w, bf2f(pv.w >> 16), a7);
    }
  }
  a0 += __shfl_xor(a0, 32); a1 += __shfl_xor(a1, 32);
  a2 += __shfl_xor(a2, 32); a3 += __shfl_xor(a3, 32);
  a4 += __shfl_xor(a4, 32); a5 += __shfl_xor(a5, 32);
  a6 += __shfl_xor(a6, 32); a7 += __shfl_xor(a7, 32);
  if (pair == 0) {
    float inv = 1.0f / sum;
    float4 b0 = ((const float4*)pbias)[2 * cl];
    float4 b1 = ((const float4*)pbias)[2 * cl + 1];
    float o0 = fmaxf(fmaf(a0, inv, b0.x), 0.f);
    float o1 = fmaxf(fmaf(a1, inv, b0.y), 0.f);
    float o2 = fmaxf(fmaf(a2, inv, b0.z), 0.f);
    float o3 = fmaxf(fmaf(a3, inv, b0.w), 0.f);
    float o4 = fmaxf(fmaf(a4, inv, b1.x), 0.f);
    float o5 = fmaxf(fmaf(a5, inv, b1.y), 0.f);
    float o6 = fmaxf(fmaf(a6, inv, b1.z), 0.f);
    float o7 = fmaxf(fmaf(a7, inv, b1.w), 0.f);
    uint4 ov = (uint4){pack2(o0, o1), pack2(o2, o3), pack2(o4, o5), pack2(o6, o7)};
    ((uint4*)outg)[(size_t)d * 32 + cl] = ov;
  }
}

// ---- layer-3 fused softmax+agg, D=10: 16-lane group per dst, p on the fly (R5 variant) ----

__global__ void agg10_fused_kernel(const int* __restrict__ off, const int* __restrict__ esrc,
                                   const float* __restrict__ as_, const float* __restrict__ ad_,
                                   const float* __restrict__ h, const float* __restrict__ bias,
                                   float* __restrict__ out) {
  int gid = blockIdx.x * 256 + threadIdx.x;
  int wid = gid >> 6, lane = threadIdx.x & 63;
  int g = lane >> 4, c = lane & 15;
  int d = wid * 4 + g;
  if (d >= N_NODES) return;
  int s0 = off[d], s1 = off[d + 1];
  float adv = ad_[d];
  float acc = 0.f, sum = 0.f;
  int s = s0;
  for (; s + 2 <= s1; s += 2) {
    int i0 = esrc[s], i1 = esrc[s + 1];
    float e0 = as_[i0] + adv; e0 = e0 > 0.f ? e0 : NEG_SLOPE * e0;
    float e1 = as_[i1] + adv; e1 = e1 > 0.f ? e1 : NEG_SLOPE * e1;
    float h0 = (c < 10) ? h[(size_t)i0 * 10 + c] : 0.f;
    float h1 = (c < 10) ? h[(size_t)i1 * 10 + c] : 0.f;
    float p0 = __expf(e0), p1 = __expf(e1);
    acc = fmaf(p0, h0, acc);
    acc = fmaf(p1, h1, acc);
    sum += p0 + p1;
  }
  if (s < s1) {
    int i0 = esrc[s];
    float e0 = as_[i0] + adv; e0 = e0 > 0.f ? e0 : NEG_SLOPE * e0;
    float p0 = __expf(e0);
    if (c < 10) acc = fmaf(p0, h[(size_t)i0 * 10 + c], acc);
    sum += p0;
  }
  if (c < 10) out[(size_t)d * 10 + c] = fmaf(acc, 1.0f / sum, bias[c]);
}

// ---------------- launch ----------------

extern "C" void kernel_launch(void* const* d_in, const int* in_sizes, int n_in,
                              void* d_out, int out_size, void* d_ws, size_t ws_size,
                              hipStream_t stream) {
  const float* x   = (const float*)d_in[0];
  const int*   ei  = (const int*)d_in[1];
  const float* W1  = (const float*)d_in[2];
  const float* as1 = (const float*)d_in[3];
  const float* ad1 = (const float*)d_in[4];
  const float* b1  = (const float*)d_in[5];
  const float* W2  = (const float*)d_in[6];
  const float* as2 = (const float*)d_in[7];
  const float* ad2 = (const float*)d_in[8];
  const float* b2  = (const float*)d_in[9];
  const float* W3  = (const float*)d_in[10];
  const float* as3 = (const float*)d_in[11];
  const float* ad3 = (const float*)d_in[12];
  const float* b3  = (const float*)d_in[13];
  float* out = (float*)d_out;

  char* ws = (char*)d_ws;
  size_t off_b = 0;
  auto alloc = [&](size_t bytes) -> char* {
    char* p = ws + off_b;
    off_b += (bytes + 255) & ~(size_t)255;
    return p;
  };
  unsigned short* hb   = (unsigned short*)alloc((size_t)N_NODES * 256 * 2);
  unsigned short* gb   = (unsigned short*)alloc((size_t)N_NODES * 256 * 2);
  unsigned short* Wf1  = (unsigned short*)alloc(256 * 256 * 2);
  unsigned short* Wf2  = (unsigned short*)alloc(256 * 256 * 2);
  unsigned short* Wf3  = (unsigned short*)alloc(8 * 64 * 8 * 2);
  float* pb1   = (float*)alloc(256 * 4);
  float* pb2   = (float*)alloc(256 * 4);
  float* h3    = (float*)alloc((size_t)N_NODES * 10 * 4);
  float* as_   = (float*)alloc((size_t)N_NODES * 4);
  float* ad_   = (float*)alloc((size_t)N_NODES * 4);
  int*   roff  = (int*)alloc((size_t)(N_NODES + 1) * 4);
  int*   cnt   = (int*)alloc((size_t)N_NODES * 4);
  int*   bsum  = (int*)alloc((size_t)SCAN_BLOCKS * 4);
  int*   bpre  = (int*)alloc((size_t)SCAN_BLOCKS * 4);
  int*   esrc  = (int*)alloc((size_t)EP * 4);

  // CSR count fused into setup (cnt zeroed first)
  hipMemsetAsync(cnt, 0, N_NODES * 4, stream);
  setup_kernel<<<67 + COUNT_BLOCKS, 256, 0, stream>>>(W1, W2, W3, b1, b2, ei,
                                                      Wf1, Wf2, Wf3, pb1, pb2, cnt);
  scan1_kernel<<<SCAN_BLOCKS, 256, 0, stream>>>(cnt, roff, bsum);
  scan2_kernel<<<1, 256, 0, stream>>>(bsum, bpre, roff);
  scan3_kernel<<<SCAN_BLOCKS, 256, 0, stream>>>(roff, bpre);
  scatter_kernel<<<COUNT_BLOCKS, 256, 0, stream>>>(ei, roff, cnt, esrc);  // atomicSub consumes cnt

  int g4blocks = (N_NODES + 223) / 224;  // 224 blocks = exactly 1 round on 256 CUs
  int g3blocks = (N_NODES + 127) / 128;  // 391
  int ablocks = (N_NODES + 3) / 4;       // 12500

  // layer 1 (A = x in f32; C permuted)
  gemm_mfma4<1><<<g4blocks, 448, 0, stream>>>(x, (const uint4*)Wf1, hb, as1, ad1, as_, ad_, N_NODES);
  agg_fused_kernel<<<ablocks, 256, 0, stream>>>(roff, esrc, as_, ad_, hb, pb1, gb);
  // layer 2 (A = gb permuted; Wf2 k-permuted to match)
  gemm_mfma4<0><<<g4blocks, 448, 0, stream>>>(gb, (const uint4*)Wf2, hb, as2, ad2, as_, ad_, N_NODES);
  agg_fused_kernel<<<ablocks, 256, 0, stream>>>(roff, esrc, as_, ad_, hb, pb2, gb);
  // layer 3 (Wf3 k-permuted)
  gemm_c3_kernel<<<g3blocks, 256, 0, stream>>>(gb, Wf3, as3, ad3, h3, as_, ad_, N_NODES);
  agg10_fused_kernel<<<ablocks, 256, 0, stream>>>(roff, esrc, as_, ad_, h3, b3, out);
}

// Round 9
// 369.759 us; speedup vs baseline: 1.1248x; 1.0114x over previous
//
#include <hip/hip_runtime.h>
#include <math.h>

#define N_NODES 50000
#define N_EDGES 800000
#define EP (N_EDGES + N_NODES) /* 850000 edges incl self-loops */
#define NEG_SLOPE 0.2f
#define SCAN_BLOCKS ((N_NODES + 255) / 256) /* 196 */
#define COUNT_BLOCKS ((EP + 255) / 256)     /* 3321 */

typedef short short8 __attribute__((ext_vector_type(8)));
typedef float float4_ __attribute__((ext_vector_type(4)));

__device__ __forceinline__ unsigned short f2bf(float f) {
  unsigned int u = __float_as_uint(f);
  u = (u + 0x7FFFu + ((u >> 16) & 1u)) >> 16;  // RNE
  return (unsigned short)u;
}
__device__ __forceinline__ float bf2f(unsigned int us) {
  return __uint_as_float(us << 16);
}
__device__ __forceinline__ unsigned int pack2(float lo, float hi) {
  return (unsigned int)f2bf(lo) | ((unsigned int)f2bf(hi) << 16);
}

// Column permutation: storage position p holds true column perm(p).
__device__ __forceinline__ int permc(int p) {
  return ((p & 0xE) << 4) | ((p & 1) << 4) | (p >> 4);
}

// ---- fused setup: W1/W2/W3 -> fragment-major bf16, bias permute, degree count ----

__global__ void setup_kernel(const float* __restrict__ W1, const float* __restrict__ W2,
                             const float* __restrict__ W3, const float* __restrict__ b1,
                             const float* __restrict__ b2, const int* __restrict__ ei,
                             unsigned short* __restrict__ Wf1, unsigned short* __restrict__ Wf2,
                             unsigned short* __restrict__ Wf3,
                             float* __restrict__ pb1, float* __restrict__ pb2,
                             int* __restrict__ cnt) {
  int blk = blockIdx.x;
  int tid = threadIdx.x;
  if (blk >= 67) {
    int e = (blk - 67) * 256 + tid;
    if (e < EP) {
      int dst = (e < N_EDGES) ? ei[N_EDGES + e] : (e - N_EDGES);
      atomicAdd(&cnt[dst], 1);
    }
    return;
  }
  if (blk < 64) {
    int perm = blk >= 32;
    const float* W = perm ? W2 : W1;
    unsigned short* Wf = perm ? Wf2 : Wf1;
    int t = (blk & 31) * 256 + tid;
    int f = t >> 6, lane = t & 63;
    int nt = f >> 3, k0t = f & 7;
    int lm = lane & 15, kg = lane >> 4;
    int kbase = k0t * 32 + kg * 8;
    int n = nt * 16 + lm;
    short8 v;
#pragma unroll
    for (int j = 0; j < 8; ++j) {
      int k = perm ? permc(kbase + j) : (kbase + j);
      v[j] = (short)f2bf(W[(size_t)k * 256 + n]);
    }
    ((short8*)Wf)[t] = v;
  } else if (blk < 66) {
    int t = (blk - 64) * 256 + tid;  // 512 threads
    int k0t = t >> 6, lane = t & 63;
    int lm = lane & 15, kg = lane >> 4;
    int kbase = k0t * 32 + kg * 8;
    short8 v;
#pragma unroll
    for (int j = 0; j < 8; ++j) {
      int k = permc(kbase + j);
      v[j] = (lm < 10) ? (short)f2bf(W3[(size_t)k * 10 + lm]) : (short)0;
    }
    ((short8*)Wf3)[t] = v;
  } else {
    int c = permc(tid);
    pb1[tid] = b1[c];
    pb2[tid] = b2[c];
  }
}

// ---------------- CSR scan + scatter ----------------

__global__ void scan1_kernel(const int* __restrict__ cnt, int* __restrict__ off,
                             int* __restrict__ bsum) {
  int i = blockIdx.x * 256 + threadIdx.x;
  int v = (i < N_NODES) ? cnt[i] : 0;
  int lane = threadIdx.x & 63, w = threadIdx.x >> 6;
  int x = v;
  for (int o = 1; o < 64; o <<= 1) { int y = __shfl_up(x, o); if (lane >= o) x += y; }
  __shared__ int wsum[4];
  if (lane == 63) wsum[w] = x;
  __syncthreads();
  int add = 0;
  for (int k = 0; k < w; ++k) add += wsum[k];
  if (i < N_NODES) off[i] = x - v + add;  // block-local exclusive
  if (threadIdx.x == 255) bsum[blockIdx.x] = add + x;
}

__global__ void scan2_kernel(int* __restrict__ bsum, int* __restrict__ bpre,
                             int* __restrict__ off) {
  int t = threadIdx.x;
  int v = (t < SCAN_BLOCKS) ? bsum[t] : 0;
  int lane = t & 63, w = t >> 6;
  int x = v;
  for (int o = 1; o < 64; o <<= 1) { int y = __shfl_up(x, o); if (lane >= o) x += y; }
  __shared__ int wsum[4];
  if (lane == 63) wsum[w] = x;
  __syncthreads();
  int add = 0;
  for (int k = 0; k < w; ++k) add += wsum[k];
  if (t < SCAN_BLOCKS) bpre[t] = x - v + add;
  if (t == 255) off[N_NODES] = add + x;  // grand total == EP
}

__global__ void scan3_kernel(int* __restrict__ off, const int* __restrict__ bpre) {
  int i = blockIdx.x * 256 + threadIdx.x;
  if (i < N_NODES) off[i] += bpre[blockIdx.x];
}

// pos = off[dst] + (atomicSub(cnt)-1): within-segment order irrelevant downstream.
__global__ void scatter_kernel(const int* __restrict__ ei, const int* __restrict__ off,
                               int* __restrict__ cnt, int* __restrict__ esrc) {
  int e = blockIdx.x * 256 + threadIdx.x;
  if (e >= EP) return;
  int src, dst;
  if (e < N_EDGES) { src = ei[e]; dst = ei[N_EDGES + e]; }
  else { src = dst = e - N_EDGES; }
  int pos = off[dst] + atomicSub(&cnt[dst], 1) - 1;
  esrc[pos] = src;
}

// ---- bf16 MFMA GEMM, B in LDS, permuted-C epilogue + fused alpha ----
// 896 threads = 14 waves x 16 rows = 224 rows/block; grid = 224 = 1 round, ~3.5 waves/SIMD.

template <int AF32>
__global__ __launch_bounds__(896, 1) void gemm_mfma5(const void* __restrict__ Av,
                                                     const uint4* __restrict__ Wf,
                                                     unsigned short* __restrict__ C,
                                                     const float* __restrict__ asrc,
                                                     const float* __restrict__ adst,
                                                     float* __restrict__ as_,
                                                     float* __restrict__ ad_, int M) {
  __shared__ uint4 Bl[8192];  // 128 KB
  int tid = threadIdx.x;
  for (int i = tid; i < 8192; i += 896) Bl[i] = Wf[i];
  int wave = tid >> 6, lane = tid & 63;
  int lm = lane & 15, kg = lane >> 4;
  int row0 = blockIdx.x * 224 + wave * 16;
  int ar = row0 + lm;
  if (ar >= M) ar = M - 1;
  float4_ acc[16];
#pragma unroll
  for (int i = 0; i < 16; ++i) acc[i] = (float4_){0, 0, 0, 0};
  __syncthreads();
  const short8* Bf = (const short8*)Bl;
  for (int k0t = 0; k0t < 8; ++k0t) {
    int k0 = k0t * 32;
    short8 a;
    if (AF32) {
      const float* A = (const float*)Av;
      const float* p = A + (size_t)ar * 256 + kg * 8 + k0;
      float4 f0 = *(const float4*)p, f1 = *(const float4*)(p + 4);
      a = (short8){(short)f2bf(f0.x), (short)f2bf(f0.y), (short)f2bf(f0.z), (short)f2bf(f0.w),
                   (short)f2bf(f1.x), (short)f2bf(f1.y), (short)f2bf(f1.z), (short)f2bf(f1.w)};
    } else {
      const unsigned short* A = (const unsigned short*)Av;
      a = *(const short8*)(A + (size_t)ar * 256 + kg * 8 + k0);
    }
#pragma unroll
    for (int nt = 0; nt < 16; ++nt) {
      short8 b = Bf[(nt * 8 + k0t) * 64 + lane];
      acc[nt] = __builtin_amdgcn_mfma_f32_16x16x32_bf16(a, b, acc[nt], 0, 0, 0);
    }
  }
  // epilogue: permuted-C coalesced stores + fused alpha (from fp32 acc, true cols)
  float avs[16], avd[16];
#pragma unroll
  for (int nt = 0; nt < 16; ++nt) { avs[nt] = asrc[nt * 16 + lm]; avd[nt] = adst[nt * 16 + lm]; }
#pragma unroll
  for (int i = 0; i < 4; ++i) {
    int r = row0 + kg * 4 + i;
    float s = 0.f, dd = 0.f;
    unsigned int u[8];
#pragma unroll
    for (int j = 0; j < 8; ++j) {
      float vlo = acc[2 * j][i];
      float vhi = acc[2 * j + 1][i];
      u[j] = pack2(vlo, vhi);
      s += vlo * avs[2 * j] + vhi * avs[2 * j + 1];
      dd += vlo * avd[2 * j] + vhi * avd[2 * j + 1];
    }
    if (r < M) {
      uint4* cp = (uint4*)(C + (size_t)r * 256 + lm * 16);
      cp[0] = (uint4){u[0], u[1], u[2], u[3]};
      cp[1] = (uint4){u[4], u[5], u[6], u[7]};
    }
#pragma unroll
    for (int o = 1; o < 16; o <<= 1) { s += __shfl_xor(s, o); dd += __shfl_xor(dd, o); }
    if (lm == 0 && r < M) { as_[r] = s; ad_[r] = dd; }
  }
}

// ---- layer-3 MFMA GEMM: 448 thr, 7 waves x 32 rows = 224 rows/block; grid 224 ----

__global__ __launch_bounds__(448) void gemm_c3_kernel(const unsigned short* __restrict__ X,
                                                      const unsigned short* __restrict__ Wf3,
                                                      const float* __restrict__ asrc,
                                                      const float* __restrict__ adst,
                                                      float* __restrict__ h3,
                                                      float* __restrict__ as_,
                                                      float* __restrict__ ad_, int M) {
  int tid = threadIdx.x;
  int wave = tid >> 6, lane = tid & 63;
  int lm = lane & 15, kg = lane >> 4;
  int row0 = blockIdx.x * 224 + wave * 32;
  int ar0 = row0 + lm, ar1 = row0 + 16 + lm;
  if (ar0 >= M) ar0 = M - 1;
  if (ar1 >= M) ar1 = M - 1;
  short8 bf[8];
#pragma unroll
  for (int k0t = 0; k0t < 8; ++k0t) bf[k0t] = ((const short8*)Wf3)[k0t * 64 + lane];
  float4_ acc0 = (float4_){0, 0, 0, 0}, acc1 = (float4_){0, 0, 0, 0};
#pragma unroll
  for (int k0t = 0; k0t < 8; ++k0t) {
    int k0 = k0t * 32;
    short8 a0 = *(const short8*)(X + (size_t)ar0 * 256 + kg * 8 + k0);
    short8 a1 = *(const short8*)(X + (size_t)ar1 * 256 + kg * 8 + k0);
    acc0 = __builtin_amdgcn_mfma_f32_16x16x32_bf16(a0, bf[k0t], acc0, 0, 0, 0);
    acc1 = __builtin_amdgcn_mfma_f32_16x16x32_bf16(a1, bf[k0t], acc1, 0, 0, 0);
  }
  float avs = (lm < 10) ? asrc[lm] : 0.f;
  float avd = (lm < 10) ? adst[lm] : 0.f;
#pragma unroll
  for (int g = 0; g < 2; ++g) {
    int rbase = row0 + g * 16 + kg * 4;
#pragma unroll
    for (int i = 0; i < 4; ++i) {
      int r = rbase + i;
      float v = g ? acc1[i] : acc0[i];
      if (r < M && lm < 10) h3[(size_t)r * 10 + lm] = v;
      float s = v * avs, dd = v * avd;
#pragma unroll
      for (int o = 1; o < 16; o <<= 1) { s += __shfl_xor(s, o); dd += __shfl_xor(dd, o); }
      if (lm == 0 && r < M) { as_[r] = s; ad_[r] = dd; }
    }
  }
}

// ---- fused softmax + aggregation (layers 1&2): one wave per dst, 2 edges/load, unroll 4 ----

__global__ __launch_bounds__(256) void agg_fused_kernel(const int* __restrict__ off,
                                                        const int* __restrict__ esrc,
                                                        const float* __restrict__ as_,
                                                        const float* __restrict__ ad_,
                                                        const unsigned short* __restrict__ h,
                                                        const float* __restrict__ pbias,
                                                        unsigned short* __restrict__ outg) {
  __shared__ int s_src[4][64];
  __shared__ float s_p[4][64];
  int wave = threadIdx.x >> 6, lane = threadIdx.x & 63;
  int pair = lane >> 5, cl = lane & 31;  // lane covers storage cols [8*cl, 8*cl+8)
  int d = blockIdx.x * 4 + wave;
  int s0 = off[d], s1 = off[d + 1];
  float adv = ad_[d];
  const uint4* hp4 = (const uint4*)h;
  float a0 = 0.f, a1 = 0.f, a2 = 0.f, a3 = 0.f, a4 = 0.f, a5 = 0.f, a6 = 0.f, a7 = 0.f;
  float sum = 0.f;
  for (int base = s0; base < s1; base += 64) {
    int m = s1 - base; if (m > 64) m = 64;
    int sv = 0; float p = 0.f;
    if (lane < m) {
      sv = esrc[base + lane];
      float e = as_[sv] + adv;
      e = e > 0.f ? e : NEG_SLOPE * e;
      p = __expf(e);
    }
    s_src[wave][lane] = sv;
    s_p[wave][lane] = p;
    float ps = p;
    for (int o = 32; o; o >>= 1) ps += __shfl_xor(ps, o);
    sum += ps;
    int nb = (m + 1) >> 1;  // batches of 2 edges (one per half-wave)
    int j = 0;
    for (; j + 4 <= nb; j += 4) {
#pragma unroll
      for (int u = 0; u < 4; ++u) {
        int idx = (j + u) * 2 + pair;
        int src = s_src[wave][idx];
        float w = s_p[wave][idx];
        uint4 pv = hp4[(size_t)src * 32 + cl];
        a0 = fmaf(w, bf2f(pv.x & 0xffffu), a0); a1 = fmaf(w, bf2f(pv.x >> 16), a1);
        a2 = fmaf(w, bf2f(pv.y & 0xffffu), a2); a3 = fmaf(w, bf2f(pv.y >> 16), a3);
        a4 = fmaf(w, bf2f(pv.z & 0xffffu), a4); a5 = fmaf(w, bf2f(pv.z >> 16), a5);
        a6 = fmaf(w, bf2f(pv.w & 0xffffu), a6); a7 = fmaf(w, bf2f(pv.w >> 16), a7);
      }
    }
    for (; j < nb; ++j) {
      int idx = j * 2 + pair;
      int src = s_src[wave][idx];
      float w = s_p[wave][idx];
      uint4 pv = hp4[(size_t)src * 32 + cl];
      a0 = fmaf(w, bf2f(pv.x & 0xffffu), a0); a1 = fmaf(w, bf2f(pv.x >> 16), a1);
      a2 = fmaf(w, bf2f(pv.y & 0xffffu), a2); a3 = fmaf(w, bf2f(pv.y >> 16), a3);
      a4 = fmaf(w, bf2f(pv.z & 0xffffu), a4); a5 = fmaf(w, bf2f(pv.z >> 16), a5);
      a6 = fmaf(w, bf2f(pv.w & 0xffffu), a6); a7 = fmaf(w, bf2f(pv.w >> 16), a7);
    }
  }
  a0 += __shfl_xor(a0, 32); a1 += __shfl_xor(a1, 32);
  a2 += __shfl_xor(a2, 32); a3 += __shfl_xor(a3, 32);
  a4 += __shfl_xor(a4, 32); a5 += __shfl_xor(a5, 32);
  a6 += __shfl_xor(a6, 32); a7 += __shfl_xor(a7, 32);
  if (pair == 0) {
    float inv = 1.0f / sum;
    float4 b0 = ((const float4*)pbias)[2 * cl];
    float4 b1 = ((const float4*)pbias)[2 * cl + 1];
    float o0 = fmaxf(fmaf(a0, inv, b0.x), 0.f);
    float o1 = fmaxf(fmaf(a1, inv, b0.y), 0.f);
    float o2 = fmaxf(fmaf(a2, inv, b0.z), 0.f);
    float o3 = fmaxf(fmaf(a3, inv, b0.w), 0.f);
    float o4 = fmaxf(fmaf(a4, inv, b1.x), 0.f);
    float o5 = fmaxf(fmaf(a5, inv, b1.y), 0.f);
    float o6 = fmaxf(fmaf(a6, inv, b1.z), 0.f);
    float o7 = fmaxf(fmaf(a7, inv, b1.w), 0.f);
    uint4 ov = (uint4){pack2(o0, o1), pack2(o2, o3), pack2(o4, o5), pack2(o6, o7)};
    ((uint4*)outg)[(size_t)d * 32 + cl] = ov;
  }
}

// ---- layer-3 fused softmax+agg, D=10: 16-lane group per dst, p on the fly ----

__global__ void agg10_fused_kernel(const int* __restrict__ off, const int* __restrict__ esrc,
                                   const float* __restrict__ as_, const float* __restrict__ ad_,
                                   const float* __restrict__ h, const float* __restrict__ bias,
                                   float* __restrict__ out) {
  int gid = blockIdx.x * 256 + threadIdx.x;
  int wid = gid >> 6, lane = threadIdx.x & 63;
  int g = lane >> 4, c = lane & 15;
  int d = wid * 4 + g;
  if (d >= N_NODES) return;
  int s0 = off[d], s1 = off[d + 1];
  float adv = ad_[d];
  float acc = 0.f, sum = 0.f;
  int s = s0;
  for (; s + 2 <= s1; s += 2) {
    int i0 = esrc[s], i1 = esrc[s + 1];
    float e0 = as_[i0] + adv; e0 = e0 > 0.f ? e0 : NEG_SLOPE * e0;
    float e1 = as_[i1] + adv; e1 = e1 > 0.f ? e1 : NEG_SLOPE * e1;
    float h0 = (c < 10) ? h[(size_t)i0 * 10 + c] : 0.f;
    float h1 = (c < 10) ? h[(size_t)i1 * 10 + c] : 0.f;
    float p0 = __expf(e0), p1 = __expf(e1);
    acc = fmaf(p0, h0, acc);
    acc = fmaf(p1, h1, acc);
    sum += p0 + p1;
  }
  if (s < s1) {
    int i0 = esrc[s];
    float e0 = as_[i0] + adv; e0 = e0 > 0.f ? e0 : NEG_SLOPE * e0;
    float p0 = __expf(e0);
    if (c < 10) acc = fmaf(p0, h[(size_t)i0 * 10 + c], acc);
    sum += p0;
  }
  if (c < 10) out[(size_t)d * 10 + c] = fmaf(acc, 1.0f / sum, bias[c]);
}

// ---------------- launch ----------------

extern "C" void kernel_launch(void* const* d_in, const int* in_sizes, int n_in,
                              void* d_out, int out_size, void* d_ws, size_t ws_size,
                              hipStream_t stream) {
  const float* x   = (const float*)d_in[0];
  const int*   ei  = (const int*)d_in[1];
  const float* W1  = (const float*)d_in[2];
  const float* as1 = (const float*)d_in[3];
  const float* ad1 = (const float*)d_in[4];
  const float* b1  = (const float*)d_in[5];
  const float* W2  = (const float*)d_in[6];
  const float* as2 = (const float*)d_in[7];
  const float* ad2 = (const float*)d_in[8];
  const float* b2  = (const float*)d_in[9];
  const float* W3  = (const float*)d_in[10];
  const float* as3 = (const float*)d_in[11];
  const float* ad3 = (const float*)d_in[12];
  const float* b3  = (const float*)d_in[13];
  float* out = (float*)d_out;

  char* ws = (char*)d_ws;
  size_t off_b = 0;
  auto alloc = [&](size_t bytes) -> char* {
    char* p = ws + off_b;
    off_b += (bytes + 255) & ~(size_t)255;
    return p;
  };
  unsigned short* hb   = (unsigned short*)alloc((size_t)N_NODES * 256 * 2);
  unsigned short* gb   = (unsigned short*)alloc((size_t)N_NODES * 256 * 2);
  unsigned short* Wf1  = (unsigned short*)alloc(256 * 256 * 2);
  unsigned short* Wf2  = (unsigned short*)alloc(256 * 256 * 2);
  unsigned short* Wf3  = (unsigned short*)alloc(8 * 64 * 8 * 2);
  float* pb1   = (float*)alloc(256 * 4);
  float* pb2   = (float*)alloc(256 * 4);
  float* h3    = (float*)alloc((size_t)N_NODES * 10 * 4);
  float* as_   = (float*)alloc((size_t)N_NODES * 4);
  float* ad_   = (float*)alloc((size_t)N_NODES * 4);
  int*   roff  = (int*)alloc((size_t)(N_NODES + 1) * 4);
  int*   cnt   = (int*)alloc((size_t)N_NODES * 4);
  int*   bsum  = (int*)alloc((size_t)SCAN_BLOCKS * 4);
  int*   bpre  = (int*)alloc((size_t)SCAN_BLOCKS * 4);
  int*   esrc  = (int*)alloc((size_t)EP * 4);

  // CSR count fused into setup (cnt zeroed first)
  hipMemsetAsync(cnt, 0, N_NODES * 4, stream);
  setup_kernel<<<67 + COUNT_BLOCKS, 256, 0, stream>>>(W1, W2, W3, b1, b2, ei,
                                                      Wf1, Wf2, Wf3, pb1, pb2, cnt);
  scan1_kernel<<<SCAN_BLOCKS, 256, 0, stream>>>(cnt, roff, bsum);
  scan2_kernel<<<1, 256, 0, stream>>>(bsum, bpre, roff);
  scan3_kernel<<<SCAN_BLOCKS, 256, 0, stream>>>(roff, bpre);
  scatter_kernel<<<COUNT_BLOCKS, 256, 0, stream>>>(ei, roff, cnt, esrc);  // atomicSub consumes cnt

  int gblocks = (N_NODES + 223) / 224;   // 224 blocks = 1 round on 256 CUs
  int ablocks = (N_NODES + 3) / 4;       // 12500

  // layer 1 (A = x in f32; C permuted)
  gemm_mfma5<1><<<gblocks, 896, 0, stream>>>(x, (const uint4*)Wf1, hb, as1, ad1, as_, ad_, N_NODES);
  agg_fused_kernel<<<ablocks, 256, 0, stream>>>(roff, esrc, as_, ad_, hb, pb1, gb);
  // layer 2 (A = gb permuted; Wf2 k-permuted to match)
  gemm_mfma5<0><<<gblocks, 896, 0, stream>>>(gb, (const uint4*)Wf2, hb, as2, ad2, as_, ad_, N_NODES);
  agg_fused_kernel<<<ablocks, 256, 0, stream>>>(roff, esrc, as_, ad_, hb, pb2, gb);
  // layer 3 (Wf3 k-permuted)
  gemm_c3_kernel<<<gblocks, 448, 0, stream>>>(gb, Wf3, as3, ad3, h3, as_, ad_, N_NODES);
  agg10_fused_kernel<<<ablocks, 256, 0, stream>>>(roff, esrc, as_, ad_, h3, b3, out);
}